// Round 2
// baseline (2183.596 us; speedup 1.0000x reference)
//
#include <hip/hip_runtime.h>

// RGCN link-prediction forward, MI355X (gfx950).
// Strategy: aggregate-then-transform. Per layer:
//   agg[r][i][:] = sum_{e: rel=r, dst=i} x[src_e]   (atomic scatter)
//   out = x@root + b + sum_r (agg[r]*inv[r]) @ W[r] (single fused GEMM, K=640)
// cnt/inv computed once (edges constant across layers). LN fused in conv3 epilogue.

constexpr int cN0 = 25000;
constexpr int cN1 = 25000;
constexpr int cN  = 50000;
constexpr int cE  = 600000;
constexpr int cD  = 128;
constexpr int cR  = 4;
constexpr int cNB = 4;

// ---------------- weight build: W[r] = sum_b comp[r,b]*bases[b] ----------------
__global__ __launch_bounds__(256)
void build_weights_kernel(const float* __restrict__ c1, const float* __restrict__ ba1,
                          const float* __restrict__ c2, const float* __restrict__ ba2,
                          const float* __restrict__ c3, const float* __restrict__ ba3,
                          float* __restrict__ W_all)
{
    int idx = blockIdx.x * 256 + threadIdx.x;
    const int per = cR * cD * cD;
    if (idx >= 3 * per) return;
    int cv  = idx / per;
    int rem = idx - cv * per;
    int r   = rem / (cD * cD);
    int io  = rem - r * (cD * cD);
    const float* comp = (cv == 0) ? c1 : (cv == 1) ? c2 : c3;
    const float* bas  = (cv == 0) ? ba1 : (cv == 1) ? ba2 : ba3;
    float s = 0.f;
#pragma unroll
    for (int b = 0; b < cNB; ++b)
        s += comp[r * cNB + b] * bas[b * cD * cD + io];
    W_all[idx] = s;
}

// ---------------- per-(rel,dst) edge counts ----------------
__global__ __launch_bounds__(256)
void count_kernel(const int* __restrict__ ei, const int* __restrict__ et,
                  int* __restrict__ cnt)
{
    int t = blockIdx.x * 256 + threadIdx.x;
    if (t >= cE) return;
    int dst = ei[cE + t];
    int rel = et[t] >> 1;
    atomicAdd(&cnt[rel * cN + dst], 1);
}

__global__ __launch_bounds__(256)
void inv_kernel(const int* __restrict__ cnt, float* __restrict__ inv)
{
    int t = blockIdx.x * 256 + threadIdx.x;
    if (t >= cR * cN) return;
    inv[t] = 1.0f / fmaxf((float)cnt[t], 1.0f);
}

// ---------------- scatter: one wave per edge, 2 floats/lane ----------------
__global__ __launch_bounds__(256)
void scatter_kernel(const float* __restrict__ x, const int* __restrict__ ei,
                    const int* __restrict__ et, float* __restrict__ agg)
{
    int e = blockIdx.x * 4 + (threadIdx.x >> 6);
    if (e >= cE) return;
    int lane = threadIdx.x & 63;
    int src = ei[e];
    int dst = ei[cE + e];
    int rel = et[e] >> 1;
    const float2 v = *(const float2*)(x + (size_t)src * cD + lane * 2);
    float* dp = agg + ((size_t)rel * cN + dst) * cD + lane * 2;
    unsafeAtomicAdd(dp,     v.x);   // global_atomic_add_f32
    unsafeAtomicAdd(dp + 1, v.y);
}

// ---------------- fused GEMM ----------------
// out[M,128]: BM=128, BN=128(full), BK=32, 256 threads, 8x8 acc per thread.
// MODE_A: 0 = contiguous [M, NSEG*128] rows (projection input)
//         1 = conv: seg0 = x rows, seg s = agg[s-1] rows scaled by inv[s-1][row]
// MODE_B: 0 = B row-major [k][o] (root then W[r] blocks)
//         1 = B = linW[o][k] (torch Linear, transposed staging)
// EPI:    0 = +bias, 1 = +bias,ReLU, 2 = +bias,LayerNorm(gamma,beta)
template<int NSEG, int MODE_A, int MODE_B, int EPI>
__global__ __launch_bounds__(256)
void gemm_kernel(const float* __restrict__ A0,
                 const float* __restrict__ Aagg,
                 const float* __restrict__ inv,
                 const float* __restrict__ B0,
                 const float* __restrict__ Wn,
                 const float* __restrict__ bias,
                 const float* __restrict__ gamma,
                 const float* __restrict__ beta,
                 float* __restrict__ out,
                 int M)
{
    __shared__ float As[32][128];   // transposed: As[k][i]
    __shared__ float Bs[32][128];   // Bs[k][o]

    const int tid = threadIdx.x;
    const int tx = tid & 15;        // 16 col-groups * 8 cols
    const int ty = tid >> 4;        // 16 row-groups * 8 rows
    const int row0 = blockIdx.x * 128;

    float acc[8][8];
#pragma unroll
    for (int m = 0; m < 8; ++m)
#pragma unroll
        for (int n = 0; n < 8; ++n) acc[m][n] = 0.f;

    const int iloc = tid & 127;
    const int kh   = tid >> 7;      // 0/1: which 16-k half this thread stages
    const int gi   = row0 + iloc;

#pragma unroll 1
    for (int ch = 0; ch < NSEG * 4; ++ch) {
        const int s  = ch >> 2;
        const int k0 = (ch & 3) * 32;

        // ---- stage A (transposed, row-scale applied) ----
        if (gi < M) {
            float scale = 1.0f;
            const float* src;
            if (MODE_A == 0) {
                src = A0 + (size_t)gi * (NSEG * 128) + s * 128 + k0 + kh * 16;
            } else if (s == 0) {
                src = A0 + (size_t)gi * 128 + k0 + kh * 16;
            } else {
                src = Aagg + ((size_t)(s - 1) * cN + gi) * 128 + k0 + kh * 16;
                scale = inv[(size_t)(s - 1) * cN + gi];
            }
#pragma unroll
            for (int j = 0; j < 4; ++j) {
                float4 t4 = *(const float4*)(src + j * 4);
                As[kh * 16 + j * 4 + 0][iloc] = t4.x * scale;
                As[kh * 16 + j * 4 + 1][iloc] = t4.y * scale;
                As[kh * 16 + j * 4 + 2][iloc] = t4.z * scale;
                As[kh * 16 + j * 4 + 3][iloc] = t4.w * scale;
            }
        } else {
#pragma unroll
            for (int j = 0; j < 16; ++j) As[kh * 16 + j][iloc] = 0.f;
        }

        // ---- stage B ----
        if (MODE_B == 0) {
            const float* bsrc = (s == 0) ? (B0 + (size_t)k0 * 128)
                                         : (Wn + ((size_t)(s - 1) * 128 + k0) * 128);
            int off = tid * 16;
            int kk = off >> 7;
            int oo = off & 127;
            const float* p = bsrc + (size_t)kk * 128 + oo;
            float4* q = (float4*)&Bs[kk][oo];
#pragma unroll
            for (int j = 0; j < 4; ++j) q[j] = *(const float4*)(p + 4 * j);
        } else {
            const int o = iloc;
            const float* p = B0 + (size_t)o * (NSEG * 128) + s * 128 + k0 + kh * 16;
#pragma unroll
            for (int j = 0; j < 4; ++j) {
                float4 t4 = *(const float4*)(p + j * 4);
                Bs[kh * 16 + j * 4 + 0][o] = t4.x;
                Bs[kh * 16 + j * 4 + 1][o] = t4.y;
                Bs[kh * 16 + j * 4 + 2][o] = t4.z;
                Bs[kh * 16 + j * 4 + 3][o] = t4.w;
            }
        }
        __syncthreads();

        // ---- compute: 8x8 outer product ----
#pragma unroll
        for (int kk = 0; kk < 32; ++kk) {
            float a[8], b[8];
            *(float4*)&a[0] = *(const float4*)&As[kk][ty * 8];
            *(float4*)&a[4] = *(const float4*)&As[kk][ty * 8 + 4];
            *(float4*)&b[0] = *(const float4*)&Bs[kk][tx * 8];
            *(float4*)&b[4] = *(const float4*)&Bs[kk][tx * 8 + 4];
#pragma unroll
            for (int m = 0; m < 8; ++m)
#pragma unroll
                for (int n = 0; n < 8; ++n)
                    acc[m][n] = fmaf(a[m], b[n], acc[m][n]);
        }
        __syncthreads();
    }

    // ---- epilogue ----
    float bi[8];
    *(float4*)&bi[0] = *(const float4*)(bias + tx * 8);
    *(float4*)&bi[4] = *(const float4*)(bias + tx * 8 + 4);

    float gm[8], bt[8];
    if (EPI == 2) {
        *(float4*)&gm[0] = *(const float4*)(gamma + tx * 8);
        *(float4*)&gm[4] = *(const float4*)(gamma + tx * 8 + 4);
        *(float4*)&bt[0] = *(const float4*)(beta + tx * 8);
        *(float4*)&bt[4] = *(const float4*)(beta + tx * 8 + 4);
    }

#pragma unroll
    for (int m = 0; m < 8; ++m) {
        int gr = row0 + ty * 8 + m;
        float v[8];
#pragma unroll
        for (int n = 0; n < 8; ++n) v[n] = acc[m][n] + bi[n];
        if (EPI == 1) {
#pragma unroll
            for (int n = 0; n < 8; ++n) v[n] = fmaxf(v[n], 0.f);
        }
        if (EPI == 2) {
            // row gr lives across the 16 tx-lanes of this ty group (contiguous lanes)
            float sm = 0.f;
#pragma unroll
            for (int n = 0; n < 8; ++n) sm += v[n];
#pragma unroll
            for (int off = 1; off < 16; off <<= 1) sm += __shfl_xor(sm, off, 64);
            float mu = sm * (1.0f / 128.0f);
            float sq = 0.f;
#pragma unroll
            for (int n = 0; n < 8; ++n) { v[n] -= mu; sq += v[n] * v[n]; }
#pragma unroll
            for (int off = 1; off < 16; off <<= 1) sq += __shfl_xor(sq, off, 64);
            float rs = rsqrtf(sq * (1.0f / 128.0f) + 1e-5f);
#pragma unroll
            for (int n = 0; n < 8; ++n) v[n] = v[n] * rs * gm[n] + bt[n];
        }
        if (gr < M) {
            float4* o0 = (float4*)(out + (size_t)gr * 128 + tx * 8);
            o0[0] = *(float4*)&v[0];
            o0[1] = *(float4*)&v[4];
        }
    }
}

extern "C" void kernel_launch(void* const* d_in, const int* in_sizes, int n_in,
                              void* d_out, int out_size, void* d_ws, size_t ws_size,
                              hipStream_t stream)
{
    (void)in_sizes; (void)n_in; (void)out_size; (void)ws_size;

    const float* x0     = (const float*)d_in[0];
    const float* x1     = (const float*)d_in[1];
    const int*   ei     = (const int*)d_in[2];
    const int*   et     = (const int*)d_in[3];
    const float* lin0_w = (const float*)d_in[4];
    const float* lin0_b = (const float*)d_in[5];
    const float* lin1_w = (const float*)d_in[6];
    const float* lin1_b = (const float*)d_in[7];
    const float* comp1  = (const float*)d_in[8];
    const float* bases1 = (const float*)d_in[9];
    const float* root1  = (const float*)d_in[10];
    const float* b1     = (const float*)d_in[11];
    const float* comp2  = (const float*)d_in[12];
    const float* bases2 = (const float*)d_in[13];
    const float* root2  = (const float*)d_in[14];
    const float* b2     = (const float*)d_in[15];
    const float* comp3  = (const float*)d_in[16];
    const float* bases3 = (const float*)d_in[17];
    const float* root3  = (const float*)d_in[18];
    const float* b3     = (const float*)d_in[19];
    const float* gamma  = (const float*)d_in[20];
    const float* beta   = (const float*)d_in[21];

    float* out = (float*)d_out;

    // workspace layout (~130.4 MB total); d_out doubles as h1/h3 buffer
    char* ws = (char*)d_ws;
    size_t off = 0;
    auto alloc = [&](size_t bytes) {
        void* p = ws + off;
        off = (off + bytes + 255) & ~(size_t)255;
        return p;
    };
    float* W_all = (float*)alloc((size_t)3 * cR * cD * cD * 4);  // 786 KB
    float* xbuf  = (float*)alloc((size_t)cN * cD * 4);           // 25.6 MB
    float* agg   = (float*)alloc((size_t)cR * cN * cD * 4);      // 102.4 MB
    float* invp  = (float*)alloc((size_t)cR * cN * 4);           // 0.8 MB
    int*   cnt   = (int*)alloc((size_t)cR * cN * 4);             // 0.8 MB

    const size_t aggBytes = (size_t)cR * cN * cD * 4;

    // ---- one-time per call: weights, counts, inverse counts ----
    build_weights_kernel<<<(3 * cR * cD * cD + 255) / 256, 256, 0, stream>>>(
        comp1, bases1, comp2, bases2, comp3, bases3, W_all);
    hipMemsetAsync(cnt, 0, (size_t)cR * cN * 4, stream);
    count_kernel<<<(cE + 255) / 256, 256, 0, stream>>>(ei, et, cnt);
    inv_kernel<<<(cR * cN + 255) / 256, 256, 0, stream>>>(cnt, invp);

    // ---- input projections -> xbuf ----
    gemm_kernel<1, 0, 1, 0><<<(cN0 + 127) / 128, 256, 0, stream>>>(
        x0, nullptr, nullptr, lin0_w, nullptr, lin0_b, nullptr, nullptr, xbuf, cN0);
    gemm_kernel<2, 0, 1, 0><<<(cN1 + 127) / 128, 256, 0, stream>>>(
        x1, nullptr, nullptr, lin1_w, nullptr, lin1_b, nullptr, nullptr,
        xbuf + (size_t)cN0 * cD, cN1);

    // ---- layer 1: xbuf -> out (ReLU) ----
    hipMemsetAsync(agg, 0, aggBytes, stream);
    scatter_kernel<<<(cE + 3) / 4, 256, 0, stream>>>(xbuf, ei, et, agg);
    gemm_kernel<5, 1, 0, 1><<<(cN + 127) / 128, 256, 0, stream>>>(
        xbuf, agg, invp, root1, W_all + (size_t)0 * cR * cD * cD, b1,
        nullptr, nullptr, out, cN);

    // ---- layer 2: out -> xbuf (ReLU) ----
    hipMemsetAsync(agg, 0, aggBytes, stream);
    scatter_kernel<<<(cE + 3) / 4, 256, 0, stream>>>(out, ei, et, agg);
    gemm_kernel<5, 1, 0, 1><<<(cN + 127) / 128, 256, 0, stream>>>(
        out, agg, invp, root2, W_all + (size_t)1 * cR * cD * cD, b2,
        nullptr, nullptr, xbuf, cN);

    // ---- layer 3: xbuf -> out (LayerNorm) ----
    hipMemsetAsync(agg, 0, aggBytes, stream);
    scatter_kernel<<<(cE + 3) / 4, 256, 0, stream>>>(xbuf, ei, et, agg);
    gemm_kernel<5, 1, 0, 2><<<(cN + 127) / 128, 256, 0, stream>>>(
        xbuf, agg, invp, root3, W_all + (size_t)2 * cR * cD * cD, b3,
        gamma, beta, out, cN);
}

// Round 6
// 922.556 us; speedup vs baseline: 2.3669x; 2.3669x over previous
//
#include <hip/hip_runtime.h>

// RGCN link-prediction forward, MI355X (gfx950).
// R3: replace per-edge fp32 atomic scatter (L2 atomic-throughput-bound, 491us x3)
// with CSR-sorted segmented mean (one wave per (rel,dst) segment, no atomics).
// CSR built once per call; reused across all 3 layers. agg holds MEANS now
// (inv fused into scatter), and agg memsets are gone (every row written once).

constexpr int cN0 = 25000;
constexpr int cN1 = 25000;
constexpr int cN  = 50000;
constexpr int cE  = 600000;
constexpr int cD  = 128;
constexpr int cR  = 4;
constexpr int cNB = 4;
constexpr int cRN = cR * cN;                 // 200000 segments
constexpr int cSCANBLK = (cRN + 255) / 256;  // 782

// ---------------- weight build: W[r] = sum_b comp[r,b]*bases[b] ----------------
__global__ __launch_bounds__(256)
void build_weights_kernel(const float* __restrict__ c1, const float* __restrict__ ba1,
                          const float* __restrict__ c2, const float* __restrict__ ba2,
                          const float* __restrict__ c3, const float* __restrict__ ba3,
                          float* __restrict__ W_all)
{
    int idx = blockIdx.x * 256 + threadIdx.x;
    const int per = cR * cD * cD;
    if (idx >= 3 * per) return;
    int cv  = idx / per;
    int rem = idx - cv * per;
    int r   = rem / (cD * cD);
    int io  = rem - r * (cD * cD);
    const float* comp = (cv == 0) ? c1 : (cv == 1) ? c2 : c3;
    const float* bas  = (cv == 0) ? ba1 : (cv == 1) ? ba2 : ba3;
    float s = 0.f;
#pragma unroll
    for (int b = 0; b < cNB; ++b)
        s += comp[r * cNB + b] * bas[b * cD * cD + io];
    W_all[idx] = s;
}

// ---------------- CSR build ----------------
__global__ __launch_bounds__(256)
void count_kernel(const int* __restrict__ ei, const int* __restrict__ et,
                  int* __restrict__ cnt)
{
    int t = blockIdx.x * 256 + threadIdx.x;
    if (t >= cE) return;
    int dst = ei[cE + t];
    int rel = et[t] >> 1;
    atomicAdd(&cnt[rel * cN + dst], 1);
}

// exclusive scan, stage 1: per-256-block scan + block sums
__global__ __launch_bounds__(256)
void scan1_kernel(const int* __restrict__ cnt, int* __restrict__ offs,
                  int* __restrict__ bsum)
{
    __shared__ int s[256];
    int t = threadIdx.x;
    int i = blockIdx.x * 256 + t;
    int v = (i < cRN) ? cnt[i] : 0;
    s[t] = v;
    __syncthreads();
#pragma unroll
    for (int off = 1; off < 256; off <<= 1) {
        int u = (t >= off) ? s[t - off] : 0;
        __syncthreads();
        s[t] += u;
        __syncthreads();
    }
    if (i < cRN) offs[i] = s[t] - v;     // exclusive within block
    if (t == 255) bsum[blockIdx.x] = s[255];
}

// stage 2: single block scans the 782 block sums (exclusive, in place)
__global__ __launch_bounds__(1024)
void scan2_kernel(int* __restrict__ bsum)
{
    __shared__ int s[1024];
    int t = threadIdx.x;
    int v = (t < cSCANBLK) ? bsum[t] : 0;
    s[t] = v;
    __syncthreads();
#pragma unroll
    for (int off = 1; off < 1024; off <<= 1) {
        int u = (t >= off) ? s[t - off] : 0;
        __syncthreads();
        s[t] += u;
        __syncthreads();
    }
    if (t < cSCANBLK) bsum[t] = s[t] - v;
}

// stage 3: add block offset; set sentinel offs[cRN] = E
__global__ __launch_bounds__(256)
void scan3_kernel(int* __restrict__ offs, const int* __restrict__ bsum)
{
    int i = blockIdx.x * 256 + threadIdx.x;
    if (i < cRN) offs[i] += bsum[blockIdx.x];
    if (i == 0) offs[cRN] = cE;
}

// fill sorted src list (fillpos reuses the cnt buffer, re-zeroed)
__global__ __launch_bounds__(256)
void fill_kernel(const int* __restrict__ ei, const int* __restrict__ et,
                 const int* __restrict__ offs, int* __restrict__ fillpos,
                 int* __restrict__ esorted)
{
    int t = blockIdx.x * 256 + threadIdx.x;
    if (t >= cE) return;
    int src = ei[t];
    int dst = ei[cE + t];
    int rel = et[t] >> 1;
    int g = rel * cN + dst;
    int p = atomicAdd(&fillpos[g], 1);
    esorted[offs[g] + p] = src;
}

// ---------------- segmented mean: one wave per (rel,dst) segment ----------------
__global__ __launch_bounds__(256)
void seg_scatter_kernel(const float* __restrict__ x, const int* __restrict__ esorted,
                        const int* __restrict__ offs, float* __restrict__ agg)
{
    int g = blockIdx.x * 4 + (threadIdx.x >> 6);
    if (g >= cRN) return;
    int lane = threadIdx.x & 63;
    int beg = offs[g], end = offs[g + 1];
    float2 acc = {0.f, 0.f};
    for (int j = beg; j < end; ++j) {
        int src = esorted[j];                       // wave-uniform -> broadcast
        const float2 v = *(const float2*)(x + (size_t)src * cD + lane * 2);
        acc.x += v.x;
        acc.y += v.y;
    }
    float invk = 1.0f / fmaxf((float)(end - beg), 1.0f);
    acc.x *= invk;
    acc.y *= invk;
    *(float2*)(agg + (size_t)g * cD + lane * 2) = acc;
}

// ---------------- fused GEMM ----------------
// out[M,128]: BM=128, BN=128(full), BK=32, 256 threads, 8x8 acc per thread.
// MODE_A: 0 = contiguous [M, NSEG*128] rows (projection input)
//         1 = conv: seg0 = x rows, seg s = agg[s-1] rows (already means)
// MODE_B: 0 = B row-major [k][o] (root then W[r] blocks)
//         1 = B = linW[o][k] (torch Linear, transposed staging)
// EPI:    0 = +bias, 1 = +bias,ReLU, 2 = +bias,LayerNorm(gamma,beta)
template<int NSEG, int MODE_A, int MODE_B, int EPI>
__global__ __launch_bounds__(256)
void gemm_kernel(const float* __restrict__ A0,
                 const float* __restrict__ Aagg,
                 const float* __restrict__ B0,
                 const float* __restrict__ Wn,
                 const float* __restrict__ bias,
                 const float* __restrict__ gamma,
                 const float* __restrict__ beta,
                 float* __restrict__ out,
                 int M)
{
    __shared__ float As[32][128];   // transposed: As[k][i]
    __shared__ float Bs[32][128];   // Bs[k][o]

    const int tid = threadIdx.x;
    const int tx = tid & 15;        // 16 col-groups * 8 cols
    const int ty = tid >> 4;        // 16 row-groups * 8 rows
    const int row0 = blockIdx.x * 128;

    float acc[8][8];
#pragma unroll
    for (int m = 0; m < 8; ++m)
#pragma unroll
        for (int n = 0; n < 8; ++n) acc[m][n] = 0.f;

    const int iloc = tid & 127;
    const int kh   = tid >> 7;      // 0/1: which 16-k half this thread stages
    const int gi   = row0 + iloc;

#pragma unroll 1
    for (int ch = 0; ch < NSEG * 4; ++ch) {
        const int s  = ch >> 2;
        const int k0 = (ch & 3) * 32;

        // ---- stage A (transposed) ----
        if (gi < M) {
            const float* src;
            if (MODE_A == 0) {
                src = A0 + (size_t)gi * (NSEG * 128) + s * 128 + k0 + kh * 16;
            } else if (s == 0) {
                src = A0 + (size_t)gi * 128 + k0 + kh * 16;
            } else {
                src = Aagg + ((size_t)(s - 1) * cN + gi) * 128 + k0 + kh * 16;
            }
#pragma unroll
            for (int j = 0; j < 4; ++j) {
                float4 t4 = *(const float4*)(src + j * 4);
                As[kh * 16 + j * 4 + 0][iloc] = t4.x;
                As[kh * 16 + j * 4 + 1][iloc] = t4.y;
                As[kh * 16 + j * 4 + 2][iloc] = t4.z;
                As[kh * 16 + j * 4 + 3][iloc] = t4.w;
            }
        } else {
#pragma unroll
            for (int j = 0; j < 16; ++j) As[kh * 16 + j][iloc] = 0.f;
        }

        // ---- stage B ----
        if (MODE_B == 0) {
            const float* bsrc = (s == 0) ? (B0 + (size_t)k0 * 128)
                                         : (Wn + ((size_t)(s - 1) * 128 + k0) * 128);
            int off = tid * 16;
            int kk = off >> 7;
            int oo = off & 127;
            const float* p = bsrc + (size_t)kk * 128 + oo;
            float4* q = (float4*)&Bs[kk][oo];
#pragma unroll
            for (int j = 0; j < 4; ++j) q[j] = *(const float4*)(p + 4 * j);
        } else {
            const int o = iloc;
            const float* p = B0 + (size_t)o * (NSEG * 128) + s * 128 + k0 + kh * 16;
#pragma unroll
            for (int j = 0; j < 4; ++j) {
                float4 t4 = *(const float4*)(p + j * 4);
                Bs[kh * 16 + j * 4 + 0][o] = t4.x;
                Bs[kh * 16 + j * 4 + 1][o] = t4.y;
                Bs[kh * 16 + j * 4 + 2][o] = t4.z;
                Bs[kh * 16 + j * 4 + 3][o] = t4.w;
            }
        }
        __syncthreads();

        // ---- compute: 8x8 outer product ----
#pragma unroll
        for (int kk = 0; kk < 32; ++kk) {
            float a[8], b[8];
            *(float4*)&a[0] = *(const float4*)&As[kk][ty * 8];
            *(float4*)&a[4] = *(const float4*)&As[kk][ty * 8 + 4];
            *(float4*)&b[0] = *(const float4*)&Bs[kk][tx * 8];
            *(float4*)&b[4] = *(const float4*)&Bs[kk][tx * 8 + 4];
#pragma unroll
            for (int m = 0; m < 8; ++m)
#pragma unroll
                for (int n = 0; n < 8; ++n)
                    acc[m][n] = fmaf(a[m], b[n], acc[m][n]);
        }
        __syncthreads();
    }

    // ---- epilogue ----
    float bi[8];
    *(float4*)&bi[0] = *(const float4*)(bias + tx * 8);
    *(float4*)&bi[4] = *(const float4*)(bias + tx * 8 + 4);

    float gm[8], bt[8];
    if (EPI == 2) {
        *(float4*)&gm[0] = *(const float4*)(gamma + tx * 8);
        *(float4*)&gm[4] = *(const float4*)(gamma + tx * 8 + 4);
        *(float4*)&bt[0] = *(const float4*)(beta + tx * 8);
        *(float4*)&bt[4] = *(const float4*)(beta + tx * 8 + 4);
    }

#pragma unroll
    for (int m = 0; m < 8; ++m) {
        int gr = row0 + ty * 8 + m;
        float v[8];
#pragma unroll
        for (int n = 0; n < 8; ++n) v[n] = acc[m][n] + bi[n];
        if (EPI == 1) {
#pragma unroll
            for (int n = 0; n < 8; ++n) v[n] = fmaxf(v[n], 0.f);
        }
        if (EPI == 2) {
            // row gr lives across the 16 tx-lanes of this ty group
            float sm = 0.f;
#pragma unroll
            for (int n = 0; n < 8; ++n) sm += v[n];
#pragma unroll
            for (int off = 1; off < 16; off <<= 1) sm += __shfl_xor(sm, off, 64);
            float mu = sm * (1.0f / 128.0f);
            float sq = 0.f;
#pragma unroll
            for (int n = 0; n < 8; ++n) { v[n] -= mu; sq += v[n] * v[n]; }
#pragma unroll
            for (int off = 1; off < 16; off <<= 1) sq += __shfl_xor(sq, off, 64);
            float rs = rsqrtf(sq * (1.0f / 128.0f) + 1e-5f);
#pragma unroll
            for (int n = 0; n < 8; ++n) v[n] = v[n] * rs * gm[n] + bt[n];
        }
        if (gr < M) {
            float4* o0 = (float4*)(out + (size_t)gr * 128 + tx * 8);
            o0[0] = *(float4*)&v[0];
            o0[1] = *(float4*)&v[4];
        }
    }
}

extern "C" void kernel_launch(void* const* d_in, const int* in_sizes, int n_in,
                              void* d_out, int out_size, void* d_ws, size_t ws_size,
                              hipStream_t stream)
{
    (void)in_sizes; (void)n_in; (void)out_size; (void)ws_size;

    const float* x0     = (const float*)d_in[0];
    const float* x1     = (const float*)d_in[1];
    const int*   ei     = (const int*)d_in[2];
    const int*   et     = (const int*)d_in[3];
    const float* lin0_w = (const float*)d_in[4];
    const float* lin0_b = (const float*)d_in[5];
    const float* lin1_w = (const float*)d_in[6];
    const float* lin1_b = (const float*)d_in[7];
    const float* comp1  = (const float*)d_in[8];
    const float* bases1 = (const float*)d_in[9];
    const float* root1  = (const float*)d_in[10];
    const float* b1     = (const float*)d_in[11];
    const float* comp2  = (const float*)d_in[12];
    const float* bases2 = (const float*)d_in[13];
    const float* root2  = (const float*)d_in[14];
    const float* b2     = (const float*)d_in[15];
    const float* comp3  = (const float*)d_in[16];
    const float* bases3 = (const float*)d_in[17];
    const float* root3  = (const float*)d_in[18];
    const float* b3     = (const float*)d_in[19];
    const float* gamma  = (const float*)d_in[20];
    const float* beta   = (const float*)d_in[21];

    float* out = (float*)d_out;

    // workspace layout (~133 MB); d_out doubles as h1/h3 buffer
    char* ws = (char*)d_ws;
    size_t off = 0;
    auto alloc = [&](size_t bytes) {
        void* p = ws + off;
        off = (off + bytes + 255) & ~(size_t)255;
        return p;
    };
    float* W_all   = (float*)alloc((size_t)3 * cR * cD * cD * 4);  // 786 KB
    float* xbuf    = (float*)alloc((size_t)cN * cD * 4);           // 25.6 MB
    float* agg     = (float*)alloc((size_t)cR * cN * cD * 4);      // 102.4 MB
    int*   offs    = (int*)alloc((size_t)(cRN + 1) * 4);           // 0.8 MB
    int*   cnt     = (int*)alloc((size_t)cRN * 4);                 // 0.8 MB (reused as fillpos)
    int*   bsum    = (int*)alloc((size_t)cSCANBLK * 4);            // 3.1 KB
    int*   esorted = (int*)alloc((size_t)cE * 4);                  // 2.4 MB

    // ---- one-time per call: weights + CSR(rel,dst) ----
    build_weights_kernel<<<(3 * cR * cD * cD + 255) / 256, 256, 0, stream>>>(
        comp1, bases1, comp2, bases2, comp3, bases3, W_all);
    hipMemsetAsync(cnt, 0, (size_t)cRN * 4, stream);
    count_kernel<<<(cE + 255) / 256, 256, 0, stream>>>(ei, et, cnt);
    scan1_kernel<<<cSCANBLK, 256, 0, stream>>>(cnt, offs, bsum);
    scan2_kernel<<<1, 1024, 0, stream>>>(bsum);
    scan3_kernel<<<cSCANBLK, 256, 0, stream>>>(offs, bsum);
    hipMemsetAsync(cnt, 0, (size_t)cRN * 4, stream);               // -> fillpos
    fill_kernel<<<(cE + 255) / 256, 256, 0, stream>>>(ei, et, offs, cnt, esorted);

    // ---- input projections -> xbuf ----
    gemm_kernel<1, 0, 1, 0><<<(cN0 + 127) / 128, 256, 0, stream>>>(
        x0, nullptr, lin0_w, nullptr, lin0_b, nullptr, nullptr, xbuf, cN0);
    gemm_kernel<2, 0, 1, 0><<<(cN1 + 127) / 128, 256, 0, stream>>>(
        x1, nullptr, lin1_w, nullptr, lin1_b, nullptr, nullptr,
        xbuf + (size_t)cN0 * cD, cN1);

    // ---- layer 1: xbuf -> out (ReLU) ----
    seg_scatter_kernel<<<(cRN + 3) / 4, 256, 0, stream>>>(xbuf, esorted, offs, agg);
    gemm_kernel<5, 1, 0, 1><<<(cN + 127) / 128, 256, 0, stream>>>(
        xbuf, agg, root1, W_all + (size_t)0 * cR * cD * cD, b1,
        nullptr, nullptr, out, cN);

    // ---- layer 2: out -> xbuf (ReLU) ----
    seg_scatter_kernel<<<(cRN + 3) / 4, 256, 0, stream>>>(out, esorted, offs, agg);
    gemm_kernel<5, 1, 0, 1><<<(cN + 127) / 128, 256, 0, stream>>>(
        out, agg, root2, W_all + (size_t)1 * cR * cD * cD, b2,
        nullptr, nullptr, xbuf, cN);

    // ---- layer 3: xbuf -> out (LayerNorm) ----
    seg_scatter_kernel<<<(cRN + 3) / 4, 256, 0, stream>>>(xbuf, esorted, offs, agg);
    gemm_kernel<5, 1, 0, 2><<<(cN + 127) / 128, 256, 0, stream>>>(
        xbuf, agg, root3, W_all + (size_t)2 * cR * cD * cD, b3,
        gamma, beta, out, cN);
}

// Round 9
// 647.162 us; speedup vs baseline: 3.3741x; 1.4255x over previous
//
#include <hip/hip_runtime.h>

// RGCN link-prediction forward, MI355X (gfx950).
// R7: conv GEMMs moved from fp32 VALU (48.8 TF, 168us ea) to bf16x3-split MFMA
// (Ahi*Bhi + Ahi*Blo + Alo*Bhi, fp32 accumulate) for ~fp32 accuracy at MFMA rate.
// W pre-built transposed [col][640] as bf16 hi/lo. LN now a separate in-place kernel.
// Scatter path (CSR segmented mean) unchanged from R6.

constexpr int cN0 = 25000;
constexpr int cN1 = 25000;
constexpr int cN  = 50000;
constexpr int cE  = 600000;
constexpr int cD  = 128;
constexpr int cR  = 4;
constexpr int cNB = 4;
constexpr int cRN = cR * cN;                 // 200000 segments
constexpr int cSCANBLK = (cRN + 255) / 256;  // 782
constexpr int cK  = 640;                     // concat K: [x | agg0..3]
constexpr int cWT = cD * cK;                 // 81920 elems per layer

typedef __attribute__((ext_vector_type(8))) short short8v;
typedef __attribute__((ext_vector_type(4))) float float4v;

// round-to-nearest-even f32 -> bf16; returns the bf16 value as f32
__device__ inline float bf_hi(float f, short& h)
{
    unsigned u = __float_as_uint(f);
    unsigned r = (u + 0x7fff + ((u >> 16) & 1)) >> 16;
    h = (short)r;
    return __uint_as_float(r << 16);
}

// ---------------- weight build: Wt[layer][col][k] hi/lo bf16 ----------------
// k<128: root[k][col]; k>=128: sum_b comp[r,b]*bases[b][kk][col], r=(k-128)/128
__global__ __launch_bounds__(256)
void build_wt_kernel(const float* __restrict__ c1, const float* __restrict__ ba1, const float* __restrict__ r1,
                     const float* __restrict__ c2, const float* __restrict__ ba2, const float* __restrict__ r2,
                     const float* __restrict__ c3, const float* __restrict__ ba3, const float* __restrict__ r3,
                     short* __restrict__ wt_hi, short* __restrict__ wt_lo)
{
    int idx = blockIdx.x * 256 + threadIdx.x;       // layer*81920 + k*128 + col
    if (idx >= 3 * cWT) return;
    int layer = idx / cWT;
    int rem   = idx - layer * cWT;
    int k     = rem >> 7;
    int col   = rem & 127;
    const float* comp = (layer == 0) ? c1 : (layer == 1) ? c2 : c3;
    const float* bas  = (layer == 0) ? ba1 : (layer == 1) ? ba2 : ba3;
    const float* root = (layer == 0) ? r1 : (layer == 1) ? r2 : r3;
    float v;
    if (k < 128) {
        v = root[k * 128 + col];
    } else {
        int r = (k - 128) >> 7, kk = (k - 128) & 127;
        v = 0.f;
#pragma unroll
        for (int b = 0; b < cNB; ++b)
            v += comp[r * cNB + b] * bas[b * 16384 + kk * 128 + col];
    }
    short h, l;
    float hf = bf_hi(v, h);
    bf_hi(v - hf, l);
    size_t o = (size_t)layer * cWT + (size_t)col * cK + k;   // transposed [col][k]
    wt_hi[o] = h;
    wt_lo[o] = l;
}

// ---------------- CSR build (unchanged, measured-good in R6) ----------------
__global__ __launch_bounds__(256)
void count_kernel(const int* __restrict__ ei, const int* __restrict__ et,
                  int* __restrict__ cnt)
{
    int t = blockIdx.x * 256 + threadIdx.x;
    if (t >= cE) return;
    int dst = ei[cE + t];
    int rel = et[t] >> 1;
    atomicAdd(&cnt[rel * cN + dst], 1);
}

__global__ __launch_bounds__(256)
void scan1_kernel(const int* __restrict__ cnt, int* __restrict__ offs,
                  int* __restrict__ bsum)
{
    __shared__ int s[256];
    int t = threadIdx.x;
    int i = blockIdx.x * 256 + t;
    int v = (i < cRN) ? cnt[i] : 0;
    s[t] = v;
    __syncthreads();
#pragma unroll
    for (int off = 1; off < 256; off <<= 1) {
        int u = (t >= off) ? s[t - off] : 0;
        __syncthreads();
        s[t] += u;
        __syncthreads();
    }
    if (i < cRN) offs[i] = s[t] - v;
    if (t == 255) bsum[blockIdx.x] = s[255];
}

__global__ __launch_bounds__(1024)
void scan2_kernel(int* __restrict__ bsum)
{
    __shared__ int s[1024];
    int t = threadIdx.x;
    int v = (t < cSCANBLK) ? bsum[t] : 0;
    s[t] = v;
    __syncthreads();
#pragma unroll
    for (int off = 1; off < 1024; off <<= 1) {
        int u = (t >= off) ? s[t - off] : 0;
        __syncthreads();
        s[t] += u;
        __syncthreads();
    }
    if (t < cSCANBLK) bsum[t] = s[t] - v;
}

__global__ __launch_bounds__(256)
void scan3_kernel(int* __restrict__ offs, const int* __restrict__ bsum)
{
    int i = blockIdx.x * 256 + threadIdx.x;
    if (i < cRN) offs[i] += bsum[blockIdx.x];
    if (i == 0) offs[cRN] = cE;
}

__global__ __launch_bounds__(256)
void fill_kernel(const int* __restrict__ ei, const int* __restrict__ et,
                 const int* __restrict__ offs, int* __restrict__ fillpos,
                 int* __restrict__ esorted)
{
    int t = blockIdx.x * 256 + threadIdx.x;
    if (t >= cE) return;
    int src = ei[t];
    int dst = ei[cE + t];
    int rel = et[t] >> 1;
    int g = rel * cN + dst;
    int p = atomicAdd(&fillpos[g], 1);
    esorted[offs[g] + p] = src;
}

// ---------------- segmented mean (unchanged) ----------------
__global__ __launch_bounds__(256)
void seg_scatter_kernel(const float* __restrict__ x, const int* __restrict__ esorted,
                        const int* __restrict__ offs, float* __restrict__ agg)
{
    int g = blockIdx.x * 4 + (threadIdx.x >> 6);
    if (g >= cRN) return;
    int lane = threadIdx.x & 63;
    int beg = offs[g], end = offs[g + 1];
    float2 acc = {0.f, 0.f};
    for (int j = beg; j < end; ++j) {
        int src = esorted[j];
        const float2 v = *(const float2*)(x + (size_t)src * cD + lane * 2);
        acc.x += v.x;
        acc.y += v.y;
    }
    float invk = 1.0f / fmaxf((float)(end - beg), 1.0f);
    acc.x *= invk;
    acc.y *= invk;
    *(float2*)(agg + (size_t)g * cD + lane * 2) = acc;
}

// ---------------- MFMA conv GEMM: out[cN][128] = [x|agg]@Wt + bias ----------------
// BM=128, BN=128, 512 thr = 8 waves (2M x 4N), K=640 in 20 steps of 32.
// bf16x3: acc += Alo*Bhi + Ahi*Blo + Ahi*Bhi. fragment: row=lane&15, k=(lane>>4)*8+j;
// C/D: col=lane&15, row=(lane>>4)*4+reg (verified mapping).
template<int EPI>  // 0: +bias; 1: +bias+ReLU
__global__ __launch_bounds__(512)
void mfma_conv_kernel(const float* __restrict__ x,
                      const float* __restrict__ agg,
                      const short* __restrict__ wt_hi,   // [128][640] this layer
                      const short* __restrict__ wt_lo,
                      const float* __restrict__ bias,
                      float* __restrict__ out)
{
    __shared__ short As_hi[128][32];
    __shared__ short As_lo[128][32];
    __shared__ short Bs_hi[128][32];
    __shared__ short Bs_lo[128][32];

    const int tid  = threadIdx.x;
    const int row0 = blockIdx.x * 128;

    // staging coords: 4 threads per row, 8 elems each
    const int srow = tid >> 2;
    const int sk8  = (tid & 3) * 8;
    const int gi   = row0 + srow;

    // wave/frag coords
    const int lane = tid & 63;
    const int wid  = tid >> 6;
    const int wm   = wid >> 2;          // 0..1
    const int wn   = wid & 3;           // 0..3
    const int fr   = lane & 15;
    const int fk   = (lane >> 4) * 8;

    float4v acc[4][2];
#pragma unroll
    for (int m = 0; m < 4; ++m)
#pragma unroll
        for (int n = 0; n < 2; ++n)
#pragma unroll
            for (int r = 0; r < 4; ++r) acc[m][n][r] = 0.f;

#pragma unroll 1
    for (int st = 0; st < 20; ++st) {
        const int s  = st >> 2;
        const int k0 = (st & 3) * 32;

        // ---- stage A: fp32 -> bf16 hi/lo ----
        short8v vh, vl;
        if (gi < cN) {
            const float* src = (s == 0)
                ? (x + (size_t)gi * cD + k0 + sk8)
                : (agg + ((size_t)(s - 1) * cN + gi) * cD + k0 + sk8);
            float4 a = *(const float4*)(src);
            float4 b = *(const float4*)(src + 4);
            float vv[8] = {a.x, a.y, a.z, a.w, b.x, b.y, b.z, b.w};
#pragma unroll
            for (int j = 0; j < 8; ++j) {
                short h, l;
                float hf = bf_hi(vv[j], h);
                bf_hi(vv[j] - hf, l);
                vh[j] = h;
                vl[j] = l;
            }
        } else {
#pragma unroll
            for (int j = 0; j < 8; ++j) { vh[j] = 0; vl[j] = 0; }
        }
        *(short8v*)&As_hi[srow][sk8] = vh;
        *(short8v*)&As_lo[srow][sk8] = vl;

        // ---- stage B: already bf16 hi/lo, transposed [col][k] ----
        const int kglob = st * 32 + sk8;
        *(short8v*)&Bs_hi[srow][sk8] = *(const short8v*)(wt_hi + (size_t)srow * cK + kglob);
        *(short8v*)&Bs_lo[srow][sk8] = *(const short8v*)(wt_lo + (size_t)srow * cK + kglob);

        __syncthreads();

        // ---- fragments ----
        short8v ah[4], al[4], bh[2], bl[2];
#pragma unroll
        for (int mf = 0; mf < 4; ++mf) {
            ah[mf] = *(const short8v*)&As_hi[wm * 64 + mf * 16 + fr][fk];
            al[mf] = *(const short8v*)&As_lo[wm * 64 + mf * 16 + fr][fk];
        }
#pragma unroll
        for (int nf = 0; nf < 2; ++nf) {
            bh[nf] = *(const short8v*)&Bs_hi[wn * 32 + nf * 16 + fr][fk];
            bl[nf] = *(const short8v*)&Bs_lo[wn * 32 + nf * 16 + fr][fk];
        }

        // ---- 24 MFMAs: lo terms first, hi*hi last ----
#pragma unroll
        for (int mf = 0; mf < 4; ++mf)
#pragma unroll
            for (int nf = 0; nf < 2; ++nf) {
                acc[mf][nf] = __builtin_amdgcn_mfma_f32_16x16x32_bf16(al[mf], bh[nf], acc[mf][nf], 0, 0, 0);
                acc[mf][nf] = __builtin_amdgcn_mfma_f32_16x16x32_bf16(ah[mf], bl[nf], acc[mf][nf], 0, 0, 0);
                acc[mf][nf] = __builtin_amdgcn_mfma_f32_16x16x32_bf16(ah[mf], bh[nf], acc[mf][nf], 0, 0, 0);
            }

        __syncthreads();
    }

    // ---- epilogue: bias (+ReLU), scalar stores (64B-coalesced per 16 lanes) ----
#pragma unroll
    for (int mf = 0; mf < 4; ++mf)
#pragma unroll
        for (int nf = 0; nf < 2; ++nf) {
            int col = wn * 32 + nf * 16 + fr;
            float bi = bias[col];
#pragma unroll
            for (int r = 0; r < 4; ++r) {
                int gr = row0 + wm * 64 + mf * 16 + (lane >> 4) * 4 + r;
                if (gr < cN) {
                    float v = acc[mf][nf][r] + bi;
                    if (EPI == 1) v = fmaxf(v, 0.f);
                    out[(size_t)gr * cD + col] = v;
                }
            }
        }
}

// ---------------- in-place LayerNorm: one wave per row ----------------
__global__ __launch_bounds__(256)
void ln_kernel(float* __restrict__ io, const float* __restrict__ gamma,
               const float* __restrict__ beta)
{
    int row = blockIdx.x * 4 + (threadIdx.x >> 6);
    if (row >= cN) return;
    int lane = threadIdx.x & 63;
    float2 v = *(const float2*)(io + (size_t)row * cD + lane * 2);
    float sm = v.x + v.y;
#pragma unroll
    for (int off = 1; off < 64; off <<= 1) sm += __shfl_xor(sm, off, 64);
    float mu = sm * (1.0f / 128.0f);
    float dx = v.x - mu, dy = v.y - mu;
    float sq = dx * dx + dy * dy;
#pragma unroll
    for (int off = 1; off < 64; off <<= 1) sq += __shfl_xor(sq, off, 64);
    float rs = rsqrtf(sq * (1.0f / 128.0f) + 1e-5f);
    float2 g = *(const float2*)(gamma + lane * 2);
    float2 b = *(const float2*)(beta + lane * 2);
    float2 o;
    o.x = dx * rs * g.x + b.x;
    o.y = dy * rs * g.y + b.y;
    *(float2*)(io + (size_t)row * cD + lane * 2) = o;
}

// ---------------- projection GEMM (fp32 VALU, unchanged structure) ----------------
// out[M,128] = A[M, NSEG*128] @ linW[o][k]^T + bias
template<int NSEG>
__global__ __launch_bounds__(256)
void proj_gemm_kernel(const float* __restrict__ A0,
                      const float* __restrict__ B0,
                      const float* __restrict__ bias,
                      float* __restrict__ out,
                      int M)
{
    __shared__ float As[32][128];
    __shared__ float Bs[32][128];

    const int tid = threadIdx.x;
    const int tx = tid & 15;
    const int ty = tid >> 4;
    const int row0 = blockIdx.x * 128;

    float acc[8][8];
#pragma unroll
    for (int m = 0; m < 8; ++m)
#pragma unroll
        for (int n = 0; n < 8; ++n) acc[m][n] = 0.f;

    const int iloc = tid & 127;
    const int kh   = tid >> 7;
    const int gi   = row0 + iloc;

#pragma unroll 1
    for (int ch = 0; ch < NSEG * 4; ++ch) {
        const int s  = ch >> 2;
        const int k0 = (ch & 3) * 32;

        if (gi < M) {
            const float* src = A0 + (size_t)gi * (NSEG * 128) + s * 128 + k0 + kh * 16;
#pragma unroll
            for (int j = 0; j < 4; ++j) {
                float4 t4 = *(const float4*)(src + j * 4);
                As[kh * 16 + j * 4 + 0][iloc] = t4.x;
                As[kh * 16 + j * 4 + 1][iloc] = t4.y;
                As[kh * 16 + j * 4 + 2][iloc] = t4.z;
                As[kh * 16 + j * 4 + 3][iloc] = t4.w;
            }
        } else {
#pragma unroll
            for (int j = 0; j < 16; ++j) As[kh * 16 + j][iloc] = 0.f;
        }

        {
            const int o = iloc;
            const float* p = B0 + (size_t)o * (NSEG * 128) + s * 128 + k0 + kh * 16;
#pragma unroll
            for (int j = 0; j < 4; ++j) {
                float4 t4 = *(const float4*)(p + j * 4);
                Bs[kh * 16 + j * 4 + 0][o] = t4.x;
                Bs[kh * 16 + j * 4 + 1][o] = t4.y;
                Bs[kh * 16 + j * 4 + 2][o] = t4.z;
                Bs[kh * 16 + j * 4 + 3][o] = t4.w;
            }
        }
        __syncthreads();

#pragma unroll
        for (int kk = 0; kk < 32; ++kk) {
            float a[8], b[8];
            *(float4*)&a[0] = *(const float4*)&As[kk][ty * 8];
            *(float4*)&a[4] = *(const float4*)&As[kk][ty * 8 + 4];
            *(float4*)&b[0] = *(const float4*)&Bs[kk][tx * 8];
            *(float4*)&b[4] = *(const float4*)&Bs[kk][tx * 8 + 4];
#pragma unroll
            for (int m = 0; m < 8; ++m)
#pragma unroll
                for (int n = 0; n < 8; ++n)
                    acc[m][n] = fmaf(a[m], b[n], acc[m][n]);
        }
        __syncthreads();
    }

    float bi[8];
    *(float4*)&bi[0] = *(const float4*)(bias + tx * 8);
    *(float4*)&bi[4] = *(const float4*)(bias + tx * 8 + 4);

#pragma unroll
    for (int m = 0; m < 8; ++m) {
        int gr = row0 + ty * 8 + m;
        if (gr < M) {
            float v[8];
#pragma unroll
            for (int n = 0; n < 8; ++n) v[n] = acc[m][n] + bi[n];
            float4* o0 = (float4*)(out + (size_t)gr * 128 + tx * 8);
            o0[0] = *(float4*)&v[0];
            o0[1] = *(float4*)&v[4];
        }
    }
}

extern "C" void kernel_launch(void* const* d_in, const int* in_sizes, int n_in,
                              void* d_out, int out_size, void* d_ws, size_t ws_size,
                              hipStream_t stream)
{
    (void)in_sizes; (void)n_in; (void)out_size; (void)ws_size;

    const float* x0     = (const float*)d_in[0];
    const float* x1     = (const float*)d_in[1];
    const int*   ei     = (const int*)d_in[2];
    const int*   et     = (const int*)d_in[3];
    const float* lin0_w = (const float*)d_in[4];
    const float* lin0_b = (const float*)d_in[5];
    const float* lin1_w = (const float*)d_in[6];
    const float* lin1_b = (const float*)d_in[7];
    const float* comp1  = (const float*)d_in[8];
    const float* bases1 = (const float*)d_in[9];
    const float* root1  = (const float*)d_in[10];
    const float* b1     = (const float*)d_in[11];
    const float* comp2  = (const float*)d_in[12];
    const float* bases2 = (const float*)d_in[13];
    const float* root2  = (const float*)d_in[14];
    const float* b2     = (const float*)d_in[15];
    const float* comp3  = (const float*)d_in[16];
    const float* bases3 = (const float*)d_in[17];
    const float* root3  = (const float*)d_in[18];
    const float* b3     = (const float*)d_in[19];
    const float* gamma  = (const float*)d_in[20];
    const float* beta   = (const float*)d_in[21];

    float* out = (float*)d_out;

    // workspace layout (~133 MB); d_out doubles as h1/h3 buffer
    char* ws = (char*)d_ws;
    size_t off = 0;
    auto alloc = [&](size_t bytes) {
        void* p = ws + off;
        off = (off + bytes + 255) & ~(size_t)255;
        return p;
    };
    float* xbuf    = (float*)alloc((size_t)cN * cD * 4);           // 25.6 MB
    float* agg     = (float*)alloc((size_t)cR * cN * cD * 4);      // 102.4 MB
    short* wt_hi   = (short*)alloc((size_t)3 * cWT * 2);           // 0.5 MB
    short* wt_lo   = (short*)alloc((size_t)3 * cWT * 2);           // 0.5 MB
    int*   offs    = (int*)alloc((size_t)(cRN + 1) * 4);           // 0.8 MB
    int*   cnt     = (int*)alloc((size_t)cRN * 4);                 // 0.8 MB (reused as fillpos)
    int*   bsum    = (int*)alloc((size_t)cSCANBLK * 4);            // 3.1 KB
    int*   esorted = (int*)alloc((size_t)cE * 4);                  // 2.4 MB

    // ---- one-time per call: transposed hi/lo weights + CSR(rel,dst) ----
    build_wt_kernel<<<(3 * cWT + 255) / 256, 256, 0, stream>>>(
        comp1, bases1, root1, comp2, bases2, root2, comp3, bases3, root3,
        wt_hi, wt_lo);
    hipMemsetAsync(cnt, 0, (size_t)cRN * 4, stream);
    count_kernel<<<(cE + 255) / 256, 256, 0, stream>>>(ei, et, cnt);
    scan1_kernel<<<cSCANBLK, 256, 0, stream>>>(cnt, offs, bsum);
    scan2_kernel<<<1, 1024, 0, stream>>>(bsum);
    scan3_kernel<<<cSCANBLK, 256, 0, stream>>>(offs, bsum);
    hipMemsetAsync(cnt, 0, (size_t)cRN * 4, stream);
    fill_kernel<<<(cE + 255) / 256, 256, 0, stream>>>(ei, et, offs, cnt, esorted);

    // ---- input projections -> xbuf ----
    proj_gemm_kernel<1><<<(cN0 + 127) / 128, 256, 0, stream>>>(
        x0, lin0_w, lin0_b, xbuf, cN0);
    proj_gemm_kernel<2><<<(cN1 + 127) / 128, 256, 0, stream>>>(
        x1, lin1_w, lin1_b, xbuf + (size_t)cN0 * cD, cN1);

    const int convGrid = (cN + 127) / 128;   // 391

    // ---- layer 1: xbuf -> out (ReLU) ----
    seg_scatter_kernel<<<(cRN + 3) / 4, 256, 0, stream>>>(xbuf, esorted, offs, agg);
    mfma_conv_kernel<1><<<convGrid, 512, 0, stream>>>(
        xbuf, agg, wt_hi + (size_t)0 * cWT, wt_lo + (size_t)0 * cWT, b1, out);

    // ---- layer 2: out -> xbuf (ReLU) ----
    seg_scatter_kernel<<<(cRN + 3) / 4, 256, 0, stream>>>(out, esorted, offs, agg);
    mfma_conv_kernel<1><<<convGrid, 512, 0, stream>>>(
        out, agg, wt_hi + (size_t)1 * cWT, wt_lo + (size_t)1 * cWT, b2, xbuf);

    // ---- layer 3: xbuf -> out (no act), then in-place LayerNorm ----
    seg_scatter_kernel<<<(cRN + 3) / 4, 256, 0, stream>>>(xbuf, esorted, offs, agg);
    mfma_conv_kernel<0><<<convGrid, 512, 0, stream>>>(
        xbuf, agg, wt_hi + (size_t)2 * cWT, wt_lo + (size_t)2 * cWT, b3, out);
    ln_kernel<<<(cN + 3) / 4, 256, 0, stream>>>(out, gamma, beta);
}

// Round 14
// 579.401 us; speedup vs baseline: 3.7687x; 1.1170x over previous
//
#include <hip/hip_runtime.h>

// RGCN link-prediction forward, MI355X (gfx950).
// R10: (a) seg_scatter: parallel esorted load + shfl broadcast + 4-wide batched
//      gathers — breaks the offs->esorted->x serial latency chain (was 84.5us,
//      VALU 22%, HBM 36% = latency-bound).
//      (b) mfma_conv: XOR granule swizzle on LDS A/B tiles (write+read) kills the
//      8-way ds_read_b128 bank conflict (row stride 64B). 2-way residual = free.
// Everything else unchanged from R9 (647us total).

constexpr int cN0 = 25000;
constexpr int cN1 = 25000;
constexpr int cN  = 50000;
constexpr int cE  = 600000;
constexpr int cD  = 128;
constexpr int cR  = 4;
constexpr int cNB = 4;
constexpr int cRN = cR * cN;                 // 200000 segments
constexpr int cSCANBLK = (cRN + 255) / 256;  // 782
constexpr int cK  = 640;                     // concat K: [x | agg0..3]
constexpr int cWT = cD * cK;                 // 81920 elems per layer

typedef __attribute__((ext_vector_type(8))) short short8v;
typedef __attribute__((ext_vector_type(4))) float float4v;

// round-to-nearest-even f32 -> bf16; returns the bf16 value as f32
__device__ inline float bf_hi(float f, short& h)
{
    unsigned u = __float_as_uint(f);
    unsigned r = (u + 0x7fff + ((u >> 16) & 1)) >> 16;
    h = (short)r;
    return __uint_as_float(r << 16);
}

// ---------------- weight build: Wt[layer][col][k] hi/lo bf16 ----------------
__global__ __launch_bounds__(256)
void build_wt_kernel(const float* __restrict__ c1, const float* __restrict__ ba1, const float* __restrict__ r1,
                     const float* __restrict__ c2, const float* __restrict__ ba2, const float* __restrict__ r2,
                     const float* __restrict__ c3, const float* __restrict__ ba3, const float* __restrict__ r3,
                     short* __restrict__ wt_hi, short* __restrict__ wt_lo)
{
    int idx = blockIdx.x * 256 + threadIdx.x;       // layer*81920 + k*128 + col
    if (idx >= 3 * cWT) return;
    int layer = idx / cWT;
    int rem   = idx - layer * cWT;
    int k     = rem >> 7;
    int col   = rem & 127;
    const float* comp = (layer == 0) ? c1 : (layer == 1) ? c2 : c3;
    const float* bas  = (layer == 0) ? ba1 : (layer == 1) ? ba2 : ba3;
    const float* root = (layer == 0) ? r1 : (layer == 1) ? r2 : r3;
    float v;
    if (k < 128) {
        v = root[k * 128 + col];
    } else {
        int r = (k - 128) >> 7, kk = (k - 128) & 127;
        v = 0.f;
#pragma unroll
        for (int b = 0; b < cNB; ++b)
            v += comp[r * cNB + b] * bas[b * 16384 + kk * 128 + col];
    }
    short h, l;
    float hf = bf_hi(v, h);
    bf_hi(v - hf, l);
    size_t o = (size_t)layer * cWT + (size_t)col * cK + k;   // transposed [col][k]
    wt_hi[o] = h;
    wt_lo[o] = l;
}

// ---------------- CSR build (unchanged) ----------------
__global__ __launch_bounds__(256)
void count_kernel(const int* __restrict__ ei, const int* __restrict__ et,
                  int* __restrict__ cnt)
{
    int t = blockIdx.x * 256 + threadIdx.x;
    if (t >= cE) return;
    int dst = ei[cE + t];
    int rel = et[t] >> 1;
    atomicAdd(&cnt[rel * cN + dst], 1);
}

__global__ __launch_bounds__(256)
void scan1_kernel(const int* __restrict__ cnt, int* __restrict__ offs,
                  int* __restrict__ bsum)
{
    __shared__ int s[256];
    int t = threadIdx.x;
    int i = blockIdx.x * 256 + t;
    int v = (i < cRN) ? cnt[i] : 0;
    s[t] = v;
    __syncthreads();
#pragma unroll
    for (int off = 1; off < 256; off <<= 1) {
        int u = (t >= off) ? s[t - off] : 0;
        __syncthreads();
        s[t] += u;
        __syncthreads();
    }
    if (i < cRN) offs[i] = s[t] - v;
    if (t == 255) bsum[blockIdx.x] = s[255];
}

__global__ __launch_bounds__(1024)
void scan2_kernel(int* __restrict__ bsum)
{
    __shared__ int s[1024];
    int t = threadIdx.x;
    int v = (t < cSCANBLK) ? bsum[t] : 0;
    s[t] = v;
    __syncthreads();
#pragma unroll
    for (int off = 1; off < 1024; off <<= 1) {
        int u = (t >= off) ? s[t - off] : 0;
        __syncthreads();
        s[t] += u;
        __syncthreads();
    }
    if (t < cSCANBLK) bsum[t] = s[t] - v;
}

__global__ __launch_bounds__(256)
void scan3_kernel(int* __restrict__ offs, const int* __restrict__ bsum)
{
    int i = blockIdx.x * 256 + threadIdx.x;
    if (i < cRN) offs[i] += bsum[blockIdx.x];
    if (i == 0) offs[cRN] = cE;
}

__global__ __launch_bounds__(256)
void fill_kernel(const int* __restrict__ ei, const int* __restrict__ et,
                 const int* __restrict__ offs, int* __restrict__ fillpos,
                 int* __restrict__ esorted)
{
    int t = blockIdx.x * 256 + threadIdx.x;
    if (t >= cE) return;
    int src = ei[t];
    int dst = ei[cE + t];
    int rel = et[t] >> 1;
    int g = rel * cN + dst;
    int p = atomicAdd(&fillpos[g], 1);
    esorted[offs[g] + p] = src;
}

// ---------------- segmented mean: parallel idx fetch + batched gathers ----------------
__global__ __launch_bounds__(256)
void seg_scatter_kernel(const float* __restrict__ x, const int* __restrict__ esorted,
                        const int* __restrict__ offs, float* __restrict__ agg)
{
    int g = blockIdx.x * 4 + (threadIdx.x >> 6);
    if (g >= cRN) return;
    int lane = threadIdx.x & 63;
    int beg = offs[g], end = offs[g + 1];
    int n = end - beg;
    float2 acc = {0.f, 0.f};
    const float* xl = x + lane * 2;

    for (int base = 0; base < n; base += 64) {
        int m = n - base;
        if (m > 64) m = 64;
        // one parallel load covers up to 64 edge indices for the whole wave
        int idx = (lane < m) ? esorted[beg + base + lane] : 0;
        // 4 gathers in flight per round; tail js clamp to a duplicate (masked add)
        for (int jb = 0; jb < m; jb += 4) {
            int j1 = (jb + 1 < m) ? jb + 1 : jb;
            int j2 = (jb + 2 < m) ? jb + 2 : jb;
            int j3 = (jb + 3 < m) ? jb + 3 : jb;
            int s0 = __shfl(idx, jb, 64);
            int s1 = __shfl(idx, j1, 64);
            int s2 = __shfl(idx, j2, 64);
            int s3 = __shfl(idx, j3, 64);
            float2 v0 = *(const float2*)(xl + (size_t)s0 * cD);
            float2 v1 = *(const float2*)(xl + (size_t)s1 * cD);
            float2 v2 = *(const float2*)(xl + (size_t)s2 * cD);
            float2 v3 = *(const float2*)(xl + (size_t)s3 * cD);
            acc.x += v0.x;
            acc.y += v0.y;
            if (jb + 1 < m) { acc.x += v1.x; acc.y += v1.y; }
            if (jb + 2 < m) { acc.x += v2.x; acc.y += v2.y; }
            if (jb + 3 < m) { acc.x += v3.x; acc.y += v3.y; }
        }
    }
    float invk = 1.0f / fmaxf((float)n, 1.0f);
    acc.x *= invk;
    acc.y *= invk;
    *(float2*)(agg + (size_t)g * cD + lane * 2) = acc;
}

// ---------------- MFMA conv GEMM with LDS XOR swizzle ----------------
// BM=128, BN=128, 512 thr = 8 waves (2M x 4N), K=640 in 20 steps of 32.
// LDS tiles [128][32] shorts; granule (8 shorts) swizzled: col = k8 ^ (((row>>1)&3)<<3).
// Read banks: lanes 0-15 hit 8 distinct 4-bank slots x2 rows = 2-way (free).
template<int EPI>  // 0: +bias; 1: +bias+ReLU
__global__ __launch_bounds__(512)
void mfma_conv_kernel(const float* __restrict__ x,
                      const float* __restrict__ agg,
                      const short* __restrict__ wt_hi,   // [128][640] this layer
                      const short* __restrict__ wt_lo,
                      const float* __restrict__ bias,
                      float* __restrict__ out)
{
    __shared__ short As_hi[128][32];
    __shared__ short As_lo[128][32];
    __shared__ short Bs_hi[128][32];
    __shared__ short Bs_lo[128][32];

    const int tid  = threadIdx.x;
    const int row0 = blockIdx.x * 128;

    // staging coords: 4 threads per row, 8 elems each
    const int srow = tid >> 2;
    const int sk8  = (tid & 3) * 8;
    const int scol = sk8 ^ (((srow >> 1) & 3) << 3);   // swizzled write col
    const int gi   = row0 + srow;

    // wave/frag coords
    const int lane = tid & 63;
    const int wid  = tid >> 6;
    const int wm   = wid >> 2;          // 0..1
    const int wn   = wid & 3;           // 0..3
    const int fr   = lane & 15;
    const int fk   = (lane >> 4) * 8;

    float4v acc[4][2];
#pragma unroll
    for (int m = 0; m < 4; ++m)
#pragma unroll
        for (int n = 0; n < 2; ++n)
#pragma unroll
            for (int r = 0; r < 4; ++r) acc[m][n][r] = 0.f;

#pragma unroll 1
    for (int st = 0; st < 20; ++st) {
        const int s  = st >> 2;
        const int k0 = (st & 3) * 32;

        // ---- stage A: fp32 -> bf16 hi/lo ----
        short8v vh, vl;
        if (gi < cN) {
            const float* src = (s == 0)
                ? (x + (size_t)gi * cD + k0 + sk8)
                : (agg + ((size_t)(s - 1) * cN + gi) * cD + k0 + sk8);
            float4 a = *(const float4*)(src);
            float4 b = *(const float4*)(src + 4);
            float vv[8] = {a.x, a.y, a.z, a.w, b.x, b.y, b.z, b.w};
#pragma unroll
            for (int j = 0; j < 8; ++j) {
                short h, l;
                float hf = bf_hi(vv[j], h);
                bf_hi(vv[j] - hf, l);
                vh[j] = h;
                vl[j] = l;
            }
        } else {
#pragma unroll
            for (int j = 0; j < 8; ++j) { vh[j] = 0; vl[j] = 0; }
        }
        *(short8v*)&As_hi[srow][scol] = vh;
        *(short8v*)&As_lo[srow][scol] = vl;

        // ---- stage B: already bf16 hi/lo, transposed [col][k] ----
        const int kglob = st * 32 + sk8;
        *(short8v*)&Bs_hi[srow][scol] = *(const short8v*)(wt_hi + (size_t)srow * cK + kglob);
        *(short8v*)&Bs_lo[srow][scol] = *(const short8v*)(wt_lo + (size_t)srow * cK + kglob);

        __syncthreads();

        // ---- fragments (swizzled read) ----
        short8v ah[4], al[4], bh[2], bl[2];
#pragma unroll
        for (int mf = 0; mf < 4; ++mf) {
            int arow = wm * 64 + mf * 16 + fr;
            int acol = fk ^ (((arow >> 1) & 3) << 3);
            ah[mf] = *(const short8v*)&As_hi[arow][acol];
            al[mf] = *(const short8v*)&As_lo[arow][acol];
        }
#pragma unroll
        for (int nf = 0; nf < 2; ++nf) {
            int brow = wn * 32 + nf * 16 + fr;
            int bcol = fk ^ (((brow >> 1) & 3) << 3);
            bh[nf] = *(const short8v*)&Bs_hi[brow][bcol];
            bl[nf] = *(const short8v*)&Bs_lo[brow][bcol];
        }

        // ---- 24 MFMAs: lo terms first, hi*hi last ----
#pragma unroll
        for (int mf = 0; mf < 4; ++mf)
#pragma unroll
            for (int nf = 0; nf < 2; ++nf) {
                acc[mf][nf] = __builtin_amdgcn_mfma_f32_16x16x32_bf16(al[mf], bh[nf], acc[mf][nf], 0, 0, 0);
                acc[mf][nf] = __builtin_amdgcn_mfma_f32_16x16x32_bf16(ah[mf], bl[nf], acc[mf][nf], 0, 0, 0);
                acc[mf][nf] = __builtin_amdgcn_mfma_f32_16x16x32_bf16(ah[mf], bh[nf], acc[mf][nf], 0, 0, 0);
            }

        __syncthreads();
    }

    // ---- epilogue: bias (+ReLU) ----
#pragma unroll
    for (int mf = 0; mf < 4; ++mf)
#pragma unroll
        for (int nf = 0; nf < 2; ++nf) {
            int col = wn * 32 + nf * 16 + fr;
            float bi = bias[col];
#pragma unroll
            for (int r = 0; r < 4; ++r) {
                int gr = row0 + wm * 64 + mf * 16 + (lane >> 4) * 4 + r;
                if (gr < cN) {
                    float v = acc[mf][nf][r] + bi;
                    if (EPI == 1) v = fmaxf(v, 0.f);
                    out[(size_t)gr * cD + col] = v;
                }
            }
        }
}

// ---------------- in-place LayerNorm: one wave per row ----------------
__global__ __launch_bounds__(256)
void ln_kernel(float* __restrict__ io, const float* __restrict__ gamma,
               const float* __restrict__ beta)
{
    int row = blockIdx.x * 4 + (threadIdx.x >> 6);
    if (row >= cN) return;
    int lane = threadIdx.x & 63;
    float2 v = *(const float2*)(io + (size_t)row * cD + lane * 2);
    float sm = v.x + v.y;
#pragma unroll
    for (int off = 1; off < 64; off <<= 1) sm += __shfl_xor(sm, off, 64);
    float mu = sm * (1.0f / 128.0f);
    float dx = v.x - mu, dy = v.y - mu;
    float sq = dx * dx + dy * dy;
#pragma unroll
    for (int off = 1; off < 64; off <<= 1) sq += __shfl_xor(sq, off, 64);
    float rs = rsqrtf(sq * (1.0f / 128.0f) + 1e-5f);
    float2 g = *(const float2*)(gamma + lane * 2);
    float2 b = *(const float2*)(beta + lane * 2);
    float2 o;
    o.x = dx * rs * g.x + b.x;
    o.y = dy * rs * g.y + b.y;
    *(float2*)(io + (size_t)row * cD + lane * 2) = o;
}

// ---------------- projection GEMM (fp32 VALU, unchanged) ----------------
template<int NSEG>
__global__ __launch_bounds__(256)
void proj_gemm_kernel(const float* __restrict__ A0,
                      const float* __restrict__ B0,
                      const float* __restrict__ bias,
                      float* __restrict__ out,
                      int M)
{
    __shared__ float As[32][128];
    __shared__ float Bs[32][128];

    const int tid = threadIdx.x;
    const int tx = tid & 15;
    const int ty = tid >> 4;
    const int row0 = blockIdx.x * 128;

    float acc[8][8];
#pragma unroll
    for (int m = 0; m < 8; ++m)
#pragma unroll
        for (int n = 0; n < 8; ++n) acc[m][n] = 0.f;

    const int iloc = tid & 127;
    const int kh   = tid >> 7;
    const int gi   = row0 + iloc;

#pragma unroll 1
    for (int ch = 0; ch < NSEG * 4; ++ch) {
        const int s  = ch >> 2;
        const int k0 = (ch & 3) * 32;

        if (gi < M) {
            const float* src = A0 + (size_t)gi * (NSEG * 128) + s * 128 + k0 + kh * 16;
#pragma unroll
            for (int j = 0; j < 4; ++j) {
                float4 t4 = *(const float4*)(src + j * 4);
                As[kh * 16 + j * 4 + 0][iloc] = t4.x;
                As[kh * 16 + j * 4 + 1][iloc] = t4.y;
                As[kh * 16 + j * 4 + 2][iloc] = t4.z;
                As[kh * 16 + j * 4 + 3][iloc] = t4.w;
            }
        } else {
#pragma unroll
            for (int j = 0; j < 16; ++j) As[kh * 16 + j][iloc] = 0.f;
        }

        {
            const int o = iloc;
            const float* p = B0 + (size_t)o * (NSEG * 128) + s * 128 + k0 + kh * 16;
#pragma unroll
            for (int j = 0; j < 4; ++j) {
                float4 t4 = *(const float4*)(p + j * 4);
                Bs[kh * 16 + j * 4 + 0][o] = t4.x;
                Bs[kh * 16 + j * 4 + 1][o] = t4.y;
                Bs[kh * 16 + j * 4 + 2][o] = t4.z;
                Bs[kh * 16 + j * 4 + 3][o] = t4.w;
            }
        }
        __syncthreads();

#pragma unroll
        for (int kk = 0; kk < 32; ++kk) {
            float a[8], b[8];
            *(float4*)&a[0] = *(const float4*)&As[kk][ty * 8];
            *(float4*)&a[4] = *(const float4*)&As[kk][ty * 8 + 4];
            *(float4*)&b[0] = *(const float4*)&Bs[kk][tx * 8];
            *(float4*)&b[4] = *(const float4*)&Bs[kk][tx * 8 + 4];
#pragma unroll
            for (int m = 0; m < 8; ++m)
#pragma unroll
                for (int n = 0; n < 8; ++n)
                    acc[m][n] = fmaf(a[m], b[n], acc[m][n]);
        }
        __syncthreads();
    }

    float bi[8];
    *(float4*)&bi[0] = *(const float4*)(bias + tx * 8);
    *(float4*)&bi[4] = *(const float4*)(bias + tx * 8 + 4);

#pragma unroll
    for (int m = 0; m < 8; ++m) {
        int gr = row0 + ty * 8 + m;
        if (gr < M) {
            float v[8];
#pragma unroll
            for (int n = 0; n < 8; ++n) v[n] = acc[m][n] + bi[n];
            float4* o0 = (float4*)(out + (size_t)gr * 128 + tx * 8);
            o0[0] = *(float4*)&v[0];
            o0[1] = *(float4*)&v[4];
        }
    }
}

extern "C" void kernel_launch(void* const* d_in, const int* in_sizes, int n_in,
                              void* d_out, int out_size, void* d_ws, size_t ws_size,
                              hipStream_t stream)
{
    (void)in_sizes; (void)n_in; (void)out_size; (void)ws_size;

    const float* x0     = (const float*)d_in[0];
    const float* x1     = (const float*)d_in[1];
    const int*   ei     = (const int*)d_in[2];
    const int*   et     = (const int*)d_in[3];
    const float* lin0_w = (const float*)d_in[4];
    const float* lin0_b = (const float*)d_in[5];
    const float* lin1_w = (const float*)d_in[6];
    const float* lin1_b = (const float*)d_in[7];
    const float* comp1  = (const float*)d_in[8];
    const float* bases1 = (const float*)d_in[9];
    const float* root1  = (const float*)d_in[10];
    const float* b1     = (const float*)d_in[11];
    const float* comp2  = (const float*)d_in[12];
    const float* bases2 = (const float*)d_in[13];
    const float* root2  = (const float*)d_in[14];
    const float* b2     = (const float*)d_in[15];
    const float* comp3  = (const float*)d_in[16];
    const float* bases3 = (const float*)d_in[17];
    const float* root3  = (const float*)d_in[18];
    const float* b3     = (const float*)d_in[19];
    const float* gamma  = (const float*)d_in[20];
    const float* beta   = (const float*)d_in[21];

    float* out = (float*)d_out;

    // workspace layout (~133 MB); d_out doubles as h1/h3 buffer
    char* ws = (char*)d_ws;
    size_t off = 0;
    auto alloc = [&](size_t bytes) {
        void* p = ws + off;
        off = (off + bytes + 255) & ~(size_t)255;
        return p;
    };
    float* xbuf    = (float*)alloc((size_t)cN * cD * 4);           // 25.6 MB
    float* agg     = (float*)alloc((size_t)cR * cN * cD * 4);      // 102.4 MB
    short* wt_hi   = (short*)alloc((size_t)3 * cWT * 2);           // 0.5 MB
    short* wt_lo   = (short*)alloc((size_t)3 * cWT * 2);           // 0.5 MB
    int*   offs    = (int*)alloc((size_t)(cRN + 1) * 4);           // 0.8 MB
    int*   cnt     = (int*)alloc((size_t)cRN * 4);                 // 0.8 MB (reused as fillpos)
    int*   bsum    = (int*)alloc((size_t)cSCANBLK * 4);            // 3.1 KB
    int*   esorted = (int*)alloc((size_t)cE * 4);                  // 2.4 MB

    // ---- one-time per call: transposed hi/lo weights + CSR(rel,dst) ----
    build_wt_kernel<<<(3 * cWT + 255) / 256, 256, 0, stream>>>(
        comp1, bases1, root1, comp2, bases2, root2, comp3, bases3, root3,
        wt_hi, wt_lo);
    hipMemsetAsync(cnt, 0, (size_t)cRN * 4, stream);
    count_kernel<<<(cE + 255) / 256, 256, 0, stream>>>(ei, et, cnt);
    scan1_kernel<<<cSCANBLK, 256, 0, stream>>>(cnt, offs, bsum);
    scan2_kernel<<<1, 1024, 0, stream>>>(bsum);
    scan3_kernel<<<cSCANBLK, 256, 0, stream>>>(offs, bsum);
    hipMemsetAsync(cnt, 0, (size_t)cRN * 4, stream);
    fill_kernel<<<(cE + 255) / 256, 256, 0, stream>>>(ei, et, offs, cnt, esorted);

    // ---- input projections -> xbuf ----
    proj_gemm_kernel<1><<<(cN0 + 127) / 128, 256, 0, stream>>>(
        x0, lin0_w, lin0_b, xbuf, cN0);
    proj_gemm_kernel<2><<<(cN1 + 127) / 128, 256, 0, stream>>>(
        x1, lin1_w, lin1_b, xbuf + (size_t)cN0 * cD, cN1);

    const int convGrid = (cN + 127) / 128;   // 391

    // ---- layer 1: xbuf -> out (ReLU) ----
    seg_scatter_kernel<<<(cRN + 3) / 4, 256, 0, stream>>>(xbuf, esorted, offs, agg);
    mfma_conv_kernel<1><<<convGrid, 512, 0, stream>>>(
        xbuf, agg, wt_hi + (size_t)0 * cWT, wt_lo + (size_t)0 * cWT, b1, out);

    // ---- layer 2: out -> xbuf (ReLU) ----
    seg_scatter_kernel<<<(cRN + 3) / 4, 256, 0, stream>>>(out, esorted, offs, agg);
    mfma_conv_kernel<1><<<convGrid, 512, 0, stream>>>(
        out, agg, wt_hi + (size_t)1 * cWT, wt_lo + (size_t)1 * cWT, b2, xbuf);

    // ---- layer 3: xbuf -> out (no act), then in-place LayerNorm ----
    seg_scatter_kernel<<<(cRN + 3) / 4, 256, 0, stream>>>(xbuf, esorted, offs, agg);
    mfma_conv_kernel<0><<<convGrid, 512, 0, stream>>>(
        xbuf, agg, wt_hi + (size_t)2 * cWT, wt_lo + (size_t)2 * cWT, b3, out);
    ln_kernel<<<(cN + 3) / 4, 256, 0, stream>>>(out, gamma, beta);
}